// Round 9
// baseline (1167.908 us; speedup 1.0000x reference)
//
#include <hip/hip_runtime.h>
#include <hip/hip_bf16.h>
#include <hip/hip_fp16.h>

// GIN 3-layer forward, MI355X (gfx950).
// R7 (2nd resubmit; bench never ran): feature-dim-split aggregation — h stored
// as two [M x 128] fp16 planes (GEMM epilogue writes planes); agg runs 2
// passes over 25.6 MB working sets instead of 1 pass over 51.2 MB. Agg time
// tracks L2-miss bytes at a fixed ~3.6 TB/s fabric rate (R1/R4/R6 evidence);
// halving the working set should raise L2 hit rate 54% -> ~65-70%.

#define DIN 128
#define DH  256
#define BM  256
#define BN  128
#define BK  64

#define BSHIFT 9
#define BNODES 512
#define MAXB   256
#define PBLK   256

// ------------------------------------------------- CSR build (counting sort)
__global__ __launch_bounds__(1024) void k_bhist(const int* __restrict__ dst,
                                                int* __restrict__ cntMat,
                                                int E, int nbuck, int chunk) {
    __shared__ int h[MAXB];
    for (int i = threadIdx.x; i < nbuck; i += 1024) h[i] = 0;
    __syncthreads();
    const int b = blockIdx.x;
    const int lo = b * chunk, hi = min(lo + chunk, E);
    for (int i = lo + (int)threadIdx.x; i < hi; i += 1024)
        atomicAdd(&h[dst[i] >> BSHIFT], 1);
    __syncthreads();
    for (int i = threadIdx.x; i < nbuck; i += 1024) cntMat[b * nbuck + i] = h[i];
}

__global__ __launch_bounds__(256) void k_bscan(const int* __restrict__ cntMat,
                                               int* __restrict__ bbase,
                                               int* __restrict__ baseMat,
                                               int nbuck, int E) {
    __shared__ int tot[MAXB];
    __shared__ int base[MAXB + 1];
    const int k = threadIdx.x;
    if (k < nbuck) {
        int s = 0;
        for (int b = 0; b < PBLK; ++b) s += cntMat[b * nbuck + k];
        tot[k] = s;
    }
    __syncthreads();
    if (k == 0) {
        int acc = 0;
        for (int i = 0; i < nbuck; ++i) { base[i] = acc; acc += tot[i]; }
        base[nbuck] = acc;
    }
    __syncthreads();
    if (k < nbuck) {
        bbase[k] = base[k];
        int acc = base[k];
        for (int b = 0; b < PBLK; ++b) { baseMat[b * nbuck + k] = acc; acc += cntMat[b * nbuck + k]; }
    }
    if (k == 0) bbase[nbuck] = E;
}

__global__ __launch_bounds__(1024) void k_bpart(const int* __restrict__ src,
                                                const int* __restrict__ dst,
                                                const int* __restrict__ baseMat,
                                                uint2* __restrict__ pairb,
                                                int E, int nbuck, int chunk) {
    __shared__ int cur[MAXB];
    const int b = blockIdx.x;
    for (int i = threadIdx.x; i < nbuck; i += 1024) cur[i] = baseMat[b * nbuck + i];
    __syncthreads();
    const int lo = b * chunk, hi = min(lo + chunk, E);
    for (int i = lo + (int)threadIdx.x; i < hi; i += 1024) {
        int d = dst[i], s = src[i];
        int pos = atomicAdd(&cur[d >> BSHIFT], 1);
        pairb[pos] = make_uint2((unsigned)d, (unsigned)s);
    }
}

__global__ __launch_bounds__(1024) void k_bcsr(const uint2* __restrict__ pairb,
                                               const int* __restrict__ bbase,
                                               int* __restrict__ rp,
                                               int* __restrict__ csr,
                                               int N, int E) {
    __shared__ int cnt[BNODES];
    __shared__ int cur[BNODES];
    const int k = blockIdx.x;
    const int node0 = k << BSHIFT;
    const int nn = min(BNODES, N - node0);
    const int lo = bbase[k], hi = bbase[k + 1];
    const int tid = threadIdx.x;

    for (int i = tid; i < BNODES; i += 1024) cnt[i] = 0;
    __syncthreads();
    for (int i = lo + tid; i < hi; i += 1024)
        atomicAdd(&cnt[pairb[i].x - node0], 1);
    __syncthreads();

    int v = 0;
    if (tid < BNODES) { v = cnt[tid]; cur[tid] = v; }
    __syncthreads();
    for (int off = 1; off < BNODES; off <<= 1) {
        int add = (tid < BNODES && tid >= off) ? cur[tid - off] : 0;
        __syncthreads();
        if (tid < BNODES) cur[tid] += add;
        __syncthreads();
    }
    if (tid < nn) {
        int start = lo + cur[tid] - v;
        rp[node0 + tid] = start;
        cur[tid] = start;
    }
    __syncthreads();
    for (int i = lo + tid; i < hi; i += 1024) {
        uint2 e = pairb[i];
        int pos = atomicAdd(&cur[e.x - node0], 1);
        csr[pos] = (int)e.y;
    }
    if (k == 0 && tid == 0) rp[N] = E;
}

// ----------------------------------------------- merged prep (wsplit + castx)
struct PrepArgs {
    const float* W[6];
    __half* Wh[6];
    const float* x;
    __half* xh;
};

// blocks [0,1408): weight transpose+cast (W0:128 blocks, W1..5: 256 each)
// blocks [1408, 1408+castBlocks): x -> fp16
__global__ __launch_bounds__(256) void k_prep(PrepArgs a, int n4) {
    int bid = blockIdx.x;
    if (bid < 1408) {
        int w, local;
        if (bid < 128) { w = 0; local = bid; }
        else { w = 1 + (bid - 128) / 256; local = (bid - 128) & 255; }
        const int K = (w == 0) ? DIN : DH;
        int idx = local * 256 + (int)threadIdx.x;
        int k = idx >> 8, c = idx & 255;
        a.Wh[w][c * K + k] = __float2half(a.W[w][idx]);
    } else {
        int i = (bid - 1408) * 256 + (int)threadIdx.x;
        if (i >= n4) return;
        float4 f = *(const float4*)(a.x + (size_t)i * 4);
        __half2 h0 = __floats2half2_rn(f.x, f.y);
        __half2 h1 = __floats2half2_rn(f.z, f.w);
        uint2 o;
        o.x = __builtin_bit_cast(unsigned, h0);
        o.y = __builtin_bit_cast(unsigned, h1);
        *(uint2*)(a.xh + (size_t)i * 4) = o;
    }
}

// ------------------------------------------------------------- aggregation
// Plane gather: Hp is [n x 128] fp16 (256 B rows). out[node*outStride+outOff
// .. +128) = Hp[node] + sum_{j->i} Hp[j].  One wave per node, 4 B/lane.
__global__ __launch_bounds__(256) void k_aggp(const __half* __restrict__ Hp,
                                              const int* __restrict__ rp,
                                              const int* __restrict__ csr,
                                              __half* __restrict__ out,
                                              int outStride, int outOff, int n) {
    int node = (int)((blockIdx.x * 256 + threadIdx.x) >> 6);
    if (node >= n) return;
    int lane = threadIdx.x & 63;
    const __half* Hl = Hp + (size_t)lane * 2;
    float a0, a1;
    {
        unsigned v = *(const unsigned*)(Hl + (size_t)node * 128);
        float2 f = __half22float2(__builtin_bit_cast(__half2, v));
        a0 = f.x; a1 = f.y;
    }
    int p = rp[node], pe = rp[node + 1];
    for (; p + 3 < pe; p += 4) {
        int j0 = csr[p], j1 = csr[p + 1], j2 = csr[p + 2], j3 = csr[p + 3];
        unsigned v0 = *(const unsigned*)(Hl + (size_t)j0 * 128);
        unsigned v1 = *(const unsigned*)(Hl + (size_t)j1 * 128);
        unsigned v2 = *(const unsigned*)(Hl + (size_t)j2 * 128);
        unsigned v3 = *(const unsigned*)(Hl + (size_t)j3 * 128);
        float2 f0 = __half22float2(__builtin_bit_cast(__half2, v0));
        float2 f1 = __half22float2(__builtin_bit_cast(__half2, v1));
        float2 f2 = __half22float2(__builtin_bit_cast(__half2, v2));
        float2 f3 = __half22float2(__builtin_bit_cast(__half2, v3));
        a0 += f0.x + f1.x + f2.x + f3.x;
        a1 += f0.y + f1.y + f2.y + f3.y;
    }
    for (; p < pe; ++p) {
        unsigned v = *(const unsigned*)(Hl + (size_t)csr[p] * 128);
        float2 f = __half22float2(__builtin_bit_cast(__half2, v));
        a0 += f.x; a1 += f.y;
    }
    __half2 o = __floats2half2_rn(a0, a1);
    *(unsigned*)(out + (size_t)node * outStride + outOff + (size_t)lane * 2) =
        __builtin_bit_cast(unsigned, o);
}

// ------------------------------------------------------------------- GEMM
// C[M x 256] = A[M x K](fp16) @ W[K x 256](fp16) + bias; fp32 accumulate.
// BM=256 BN=128 BK=64, 4 waves, wave-tile 128x64. XOR-swizzled LDS.
// MODE 0: fp16 [M x 256] + relu; MODE 1: fp32 [M x 256]; MODE 2: fp16 + relu
// into two [M x 128] planes (blockIdx.y selects plane).
typedef __attribute__((ext_vector_type(8))) _Float16 f16x8;
typedef __attribute__((ext_vector_type(4))) float     f32x4;

template<int K, int MODE>
__global__ __launch_bounds__(256, 2) void k_gemm_mfma(
        const __half* __restrict__ A,    // [Mpad x K]
        const __half* __restrict__ Wt,   // [256 x K] (transposed W)
        const float* __restrict__ bias,
        void* __restrict__ Cout, void* __restrict__ Cout2, int M) {
    __shared__ __align__(16) __half As[BM * BK];   // 32 KB
    __shared__ __align__(16) __half Ws[BN * BK];   // 16 KB

    const int t    = threadIdx.x;
    const int lane = t & 63;
    const int wid  = t >> 6;
    const int wr   = wid >> 1;
    const int wc   = wid & 1;
    const int brow = (int)blockIdx.x * BM;
    const int bcol = (int)blockIdx.y * BN;

    f32x4 acc[8][4] = {};

    for (int k0 = 0; k0 < K; k0 += BK) {
#pragma unroll
        for (int i = 0; i < 8; ++i) {
            int idx = i * 256 + t;
            int r = idx >> 3, q = idx & 7;
            uint4 v = *(const uint4*)(A + (size_t)(brow + r) * K + k0 + q * 8);
            *(uint4*)((char*)As + r * 128 + ((q ^ (r & 7)) << 4)) = v;
        }
#pragma unroll
        for (int i = 0; i < 4; ++i) {
            int idx = i * 256 + t;
            int c = idx >> 3, q = idx & 7;
            uint4 vh = *(const uint4*)(Wt + (size_t)(bcol + c) * K + k0 + q * 8);
            *(uint4*)((char*)Ws + c * 128 + ((q ^ (c & 7)) << 4)) = vh;
        }
        __syncthreads();

#pragma unroll
        for (int kk = 0; kk < 2; ++kk) {
            const int qa = kk * 4 + (lane >> 4);
            f16x8 af[8], wf[4];
#pragma unroll
            for (int mi = 0; mi < 8; ++mi) {
                int r = wr * 128 + mi * 16 + (lane & 15);
                af[mi] = *(const f16x8*)((const char*)As + r * 128 + ((qa ^ (r & 7)) << 4));
            }
#pragma unroll
            for (int ni = 0; ni < 4; ++ni) {
                int c = wc * 64 + ni * 16 + (lane & 15);
                wf[ni] = *(const f16x8*)((const char*)Ws + c * 128 + ((qa ^ (c & 7)) << 4));
            }
#pragma unroll
            for (int mi = 0; mi < 8; ++mi)
#pragma unroll
                for (int ni = 0; ni < 4; ++ni)
                    acc[mi][ni] = __builtin_amdgcn_mfma_f32_16x16x32_f16(af[mi], wf[ni], acc[mi][ni], 0, 0, 0);
        }
        __syncthreads();
    }

    __half* Plane = (__half*)(blockIdx.y == 0 ? Cout : Cout2);  // MODE 2 only
#pragma unroll
    for (int ni = 0; ni < 4; ++ni) {
        const int cl = wc * 64 + ni * 16 + (lane & 15);   // 0..127 within block
        const int c  = bcol + cl;
        const float bz = bias[c];
#pragma unroll
        for (int mi = 0; mi < 8; ++mi) {
            const int r0 = brow + wr * 128 + mi * 16 + ((lane >> 4) << 2);
#pragma unroll
            for (int j = 0; j < 4; ++j) {
                int row = r0 + j;
                if (row < M) {
                    float v = acc[mi][ni][j] + bz;
                    if (MODE == 0) {
                        v = fmaxf(v, 0.f);
                        ((__half*)Cout)[(size_t)row * DH + c] = __float2half(v);
                    } else if (MODE == 1) {
                        ((float*)Cout)[(size_t)row * DH + c] = v;
                    } else {
                        v = fmaxf(v, 0.f);
                        Plane[(size_t)row * 128 + cl] = __float2half(v);
                    }
                }
            }
        }
    }
}

// ------------------------------------------------------------------ launch
static inline size_t align256(size_t x) { return (x + 255) & ~(size_t)255; }

extern "C" void kernel_launch(void* const* d_in, const int* in_sizes, int n_in,
                              void* d_out, int out_size, void* d_ws, size_t ws_size,
                              hipStream_t stream) {
    const float* x   = (const float*)d_in[0];
    const int*   ei  = (const int*)d_in[1];
    const float* W[6]  = {(const float*)d_in[2], (const float*)d_in[4],
                          (const float*)d_in[6], (const float*)d_in[8],
                          (const float*)d_in[10], (const float*)d_in[12]};
    const float* Bv[6] = {(const float*)d_in[3], (const float*)d_in[5],
                          (const float*)d_in[7], (const float*)d_in[9],
                          (const float*)d_in[11], (const float*)d_in[13]};

    const int N = in_sizes[0] / DIN;
    const int E = in_sizes[1] / 2;
    const int Mpad = ((N + BM - 1) / BM) * BM;
    const int* src = ei;
    const int* dst = ei + E;
    const int nbuck  = (N + BNODES - 1) / BNODES;
    const int chunkE = (E + PBLK - 1) / PBLK;

    char* ws = (char*)d_ws;
    __half* A1  = (__half*)ws; ws += align256((size_t)Mpad * DIN * 2);
    __half* Ah  = (__half*)ws; ws += align256((size_t)Mpad * DH * 2);
    __half* T   = (__half*)ws; ws += align256((size_t)Mpad * DH * 2);
    __half* Hp0 = (__half*)ws; ws += align256((size_t)Mpad * 128 * 2);
    __half* Hp1 = (__half*)ws; ws += align256((size_t)Mpad * 128 * 2);
    __half* Xh = (__half*)T;          // alias: T first written after Xh last read
    uint2* pairb = (uint2*)Ah;        // alias: Ah first written after pairb dead
    __half* Wh[6];
    const int Ks[6] = {DIN, DH, DH, DH, DH, DH};
    for (int i = 0; i < 6; ++i) {
        Wh[i] = (__half*)ws; ws += align256((size_t)Ks[i] * DH * 2);
    }
    int* cntMat  = (int*)ws; ws += align256((size_t)PBLK * MAXB * 4);
    int* baseMat = (int*)ws; ws += align256((size_t)PBLK * MAXB * 4);
    int* bbase   = (int*)ws; ws += align256((size_t)(MAXB + 1) * 4);
    int* rp      = (int*)ws; ws += align256((size_t)(N + 1) * 4);
    int* csr     = (int*)ws; ws += align256((size_t)E * 4);
    float* O = (float*)d_out;

    // --- merged prep (weight transpose/cast + x cast) ---
    PrepArgs pa;
    for (int i = 0; i < 6; ++i) { pa.W[i] = W[i]; pa.Wh[i] = Wh[i]; }
    pa.x = x; pa.xh = Xh;
    const int n4 = N * DIN / 4;
    const int castBlocks = (n4 + 255) / 256;
    k_prep<<<1408 + castBlocks, 256, 0, stream>>>(pa, n4);

    // --- CSR build (counting sort; no global atomics) ---
    k_bhist<<<PBLK, 1024, 0, stream>>>(dst, cntMat, E, nbuck, chunkE);
    k_bscan<<<1, 256, 0, stream>>>(cntMat, bbase, baseMat, nbuck, E);
    k_bpart<<<PBLK, 1024, 0, stream>>>(src, dst, baseMat, pairb, E, nbuck, chunkE);
    k_bcsr<<<nbuck, 1024, 0, stream>>>(pairb, bbase, rp, csr, N, E);

    const int gAgg = (N + 3) / 4;
    dim3 gGemm(Mpad / BM, DH / BN);

    // --- layer 1 ---
    k_aggp<<<gAgg, 256, 0, stream>>>(Xh, rp, csr, A1, 128, 0, N);
    k_gemm_mfma<DIN, 0><<<gGemm, 256, 0, stream>>>(A1, Wh[0], Bv[0], T, nullptr, N);
    k_gemm_mfma<DH,  2><<<gGemm, 256, 0, stream>>>(T,  Wh[1], Bv[1], Hp0, Hp1, N);
    // --- layer 2 ---
    k_aggp<<<gAgg, 256, 0, stream>>>(Hp0, rp, csr, Ah, 256, 0,   N);
    k_aggp<<<gAgg, 256, 0, stream>>>(Hp1, rp, csr, Ah, 256, 128, N);
    k_gemm_mfma<DH,  0><<<gGemm, 256, 0, stream>>>(Ah, Wh[2], Bv[2], T, nullptr, N);
    k_gemm_mfma<DH,  2><<<gGemm, 256, 0, stream>>>(T,  Wh[3], Bv[3], Hp0, Hp1, N);
    // --- layer 3 ---
    k_aggp<<<gAgg, 256, 0, stream>>>(Hp0, rp, csr, Ah, 256, 0,   N);
    k_aggp<<<gAgg, 256, 0, stream>>>(Hp1, rp, csr, Ah, 256, 128, N);
    k_gemm_mfma<DH,  0><<<gGemm, 256, 0, stream>>>(Ah, Wh[4], Bv[4], T, nullptr, N);
    k_gemm_mfma<DH,  1><<<gGemm, 256, 0, stream>>>(T,  Wh[5], Bv[5], O, nullptr, N);
}

// Round 10
// 1127.851 us; speedup vs baseline: 1.0355x; 1.0355x over previous
//
#include <hip/hip_runtime.h>
#include <hip/hip_bf16.h>
#include <hip/hip_fp16.h>

// GIN 3-layer forward, MI355X (gfx950).
// R10: revert plane-split (R9 refuted ws->hit-rate model: FETCH halved but
// rate fixed ~3.5 TB/s; extra pass cost > gain). Agg = R6 measured-best form.
// GEMM staging -> global_load_lds width=16 (async, no VGPR roundtrip), XOR
// swizzle preserved via pre-swizzled per-lane GLOBAL source + linear LDS dest
// (lane l -> base + l*16 == row ti*8+(l>>3), chunk l&7).

#define DIN 128
#define DH  256
#define BM  256
#define BN  128
#define BK  64

#define BSHIFT 9
#define BNODES 512
#define MAXB   256
#define PBLK   256

// ------------------------------------------------- CSR build (counting sort)
__global__ __launch_bounds__(1024) void k_bhist(const int* __restrict__ dst,
                                                int* __restrict__ cntMat,
                                                int E, int nbuck, int chunk) {
    __shared__ int h[MAXB];
    for (int i = threadIdx.x; i < nbuck; i += 1024) h[i] = 0;
    __syncthreads();
    const int b = blockIdx.x;
    const int lo = b * chunk, hi = min(lo + chunk, E);
    for (int i = lo + (int)threadIdx.x; i < hi; i += 1024)
        atomicAdd(&h[dst[i] >> BSHIFT], 1);
    __syncthreads();
    for (int i = threadIdx.x; i < nbuck; i += 1024) cntMat[b * nbuck + i] = h[i];
}

__global__ __launch_bounds__(256) void k_bscan(const int* __restrict__ cntMat,
                                               int* __restrict__ bbase,
                                               int* __restrict__ baseMat,
                                               int nbuck, int E) {
    __shared__ int tot[MAXB];
    __shared__ int base[MAXB + 1];
    const int k = threadIdx.x;
    if (k < nbuck) {
        int s = 0;
        for (int b = 0; b < PBLK; ++b) s += cntMat[b * nbuck + k];
        tot[k] = s;
    }
    __syncthreads();
    if (k == 0) {
        int acc = 0;
        for (int i = 0; i < nbuck; ++i) { base[i] = acc; acc += tot[i]; }
        base[nbuck] = acc;
    }
    __syncthreads();
    if (k < nbuck) {
        bbase[k] = base[k];
        int acc = base[k];
        for (int b = 0; b < PBLK; ++b) { baseMat[b * nbuck + k] = acc; acc += cntMat[b * nbuck + k]; }
    }
    if (k == 0) bbase[nbuck] = E;
}

__global__ __launch_bounds__(1024) void k_bpart(const int* __restrict__ src,
                                                const int* __restrict__ dst,
                                                const int* __restrict__ baseMat,
                                                uint2* __restrict__ pairb,
                                                int E, int nbuck, int chunk) {
    __shared__ int cur[MAXB];
    const int b = blockIdx.x;
    for (int i = threadIdx.x; i < nbuck; i += 1024) cur[i] = baseMat[b * nbuck + i];
    __syncthreads();
    const int lo = b * chunk, hi = min(lo + chunk, E);
    for (int i = lo + (int)threadIdx.x; i < hi; i += 1024) {
        int d = dst[i], s = src[i];
        int pos = atomicAdd(&cur[d >> BSHIFT], 1);
        pairb[pos] = make_uint2((unsigned)d, (unsigned)s);
    }
}

__global__ __launch_bounds__(1024) void k_bcsr(const uint2* __restrict__ pairb,
                                               const int* __restrict__ bbase,
                                               int* __restrict__ rp,
                                               int* __restrict__ csr,
                                               int N, int E) {
    __shared__ int cnt[BNODES];
    __shared__ int cur[BNODES];
    const int k = blockIdx.x;
    const int node0 = k << BSHIFT;
    const int nn = min(BNODES, N - node0);
    const int lo = bbase[k], hi = bbase[k + 1];
    const int tid = threadIdx.x;

    for (int i = tid; i < BNODES; i += 1024) cnt[i] = 0;
    __syncthreads();
    for (int i = lo + tid; i < hi; i += 1024)
        atomicAdd(&cnt[pairb[i].x - node0], 1);
    __syncthreads();

    int v = 0;
    if (tid < BNODES) { v = cnt[tid]; cur[tid] = v; }
    __syncthreads();
    for (int off = 1; off < BNODES; off <<= 1) {
        int add = (tid < BNODES && tid >= off) ? cur[tid - off] : 0;
        __syncthreads();
        if (tid < BNODES) cur[tid] += add;
        __syncthreads();
    }
    if (tid < nn) {
        int start = lo + cur[tid] - v;
        rp[node0 + tid] = start;
        cur[tid] = start;
    }
    __syncthreads();
    for (int i = lo + tid; i < hi; i += 1024) {
        uint2 e = pairb[i];
        int pos = atomicAdd(&cur[e.x - node0], 1);
        csr[pos] = (int)e.y;
    }
    if (k == 0 && tid == 0) rp[N] = E;
}

// ----------------------------------------------- merged prep (wsplit + castx)
struct PrepArgs {
    const float* W[6];
    __half* Wh[6];
    const float* x;
    __half* xh;
};

__global__ __launch_bounds__(256) void k_prep(PrepArgs a, int n4) {
    int bid = blockIdx.x;
    if (bid < 1408) {
        int w, local;
        if (bid < 128) { w = 0; local = bid; }
        else { w = 1 + (bid - 128) / 256; local = (bid - 128) & 255; }
        const int K = (w == 0) ? DIN : DH;
        int idx = local * 256 + (int)threadIdx.x;
        int k = idx >> 8, c = idx & 255;
        a.Wh[w][c * K + k] = __float2half(a.W[w][idx]);
    } else {
        int i = (bid - 1408) * 256 + (int)threadIdx.x;
        if (i >= n4) return;
        float4 f = *(const float4*)(a.x + (size_t)i * 4);
        __half2 h0 = __floats2half2_rn(f.x, f.y);
        __half2 h1 = __floats2half2_rn(f.z, f.w);
        uint2 o;
        o.x = __builtin_bit_cast(unsigned, h0);
        o.y = __builtin_bit_cast(unsigned, h1);
        *(uint2*)(a.xh + (size_t)i * 4) = o;
    }
}

// ------------------------------------------------------------- aggregation
__device__ __forceinline__ void addrow4(unsigned lo, unsigned hi,
                                        float& a0, float& a1, float& a2, float& a3) {
    __half2 h0 = __builtin_bit_cast(__half2, lo);
    __half2 h1 = __builtin_bit_cast(__half2, hi);
    float2 f0 = __half22float2(h0);
    float2 f1 = __half22float2(h1);
    a0 += f0.x; a1 += f0.y; a2 += f1.x; a3 += f1.y;
}

// out[i] = h[i] + sum_{j->i} h[j]; H fp16 [Mpad x 256]; one wave per node.
__global__ __launch_bounds__(256) void k_aggh256(const __half* __restrict__ H,
                                                 const int* __restrict__ rp,
                                                 const int* __restrict__ csr,
                                                 __half* __restrict__ out, int n) {
    int node = (int)((blockIdx.x * 256 + threadIdx.x) >> 6);
    if (node >= n) return;
    int lane = threadIdx.x & 63;
    const size_t lo4 = (size_t)lane * 4;
    float a0, a1, a2, a3;
    {
        uint2 v = *(const uint2*)(H + (size_t)node * DH + lo4);
        a0 = a1 = a2 = a3 = 0.f;
        addrow4(v.x, v.y, a0, a1, a2, a3);
    }
    int p = rp[node], pe = rp[node + 1];
    for (; p + 3 < pe; p += 4) {
        int j0 = csr[p], j1 = csr[p + 1], j2 = csr[p + 2], j3 = csr[p + 3];
        uint2 v0 = *(const uint2*)(H + (size_t)j0 * DH + lo4);
        uint2 v1 = *(const uint2*)(H + (size_t)j1 * DH + lo4);
        uint2 v2 = *(const uint2*)(H + (size_t)j2 * DH + lo4);
        uint2 v3 = *(const uint2*)(H + (size_t)j3 * DH + lo4);
        addrow4(v0.x, v0.y, a0, a1, a2, a3);
        addrow4(v1.x, v1.y, a0, a1, a2, a3);
        addrow4(v2.x, v2.y, a0, a1, a2, a3);
        addrow4(v3.x, v3.y, a0, a1, a2, a3);
    }
    for (; p < pe; ++p) {
        uint2 v = *(const uint2*)(H + (size_t)csr[p] * DH + lo4);
        addrow4(v.x, v.y, a0, a1, a2, a3);
    }
    __half2 o0 = __floats2half2_rn(a0, a1);
    __half2 o1 = __floats2half2_rn(a2, a3);
    uint2 ov;
    ov.x = __builtin_bit_cast(unsigned, o0);
    ov.y = __builtin_bit_cast(unsigned, o1);
    *(uint2*)(out + (size_t)node * DH + lo4) = ov;
}

// layer-1: gather fp16 x-table [N x 128]; 4B/lane.
__global__ __launch_bounds__(256) void k_aggh128(const __half* __restrict__ H,
                                                 const int* __restrict__ rp,
                                                 const int* __restrict__ csr,
                                                 __half* __restrict__ out, int n) {
    int node = (int)((blockIdx.x * 256 + threadIdx.x) >> 6);
    if (node >= n) return;
    int lane = threadIdx.x & 63;
    const size_t lo2 = (size_t)lane * 2;
    float a0, a1;
    {
        unsigned v = *(const unsigned*)(H + (size_t)node * DIN + lo2);
        float2 f = __half22float2(__builtin_bit_cast(__half2, v));
        a0 = f.x; a1 = f.y;
    }
    int p = rp[node], pe = rp[node + 1];
    for (; p + 3 < pe; p += 4) {
        int j0 = csr[p], j1 = csr[p + 1], j2 = csr[p + 2], j3 = csr[p + 3];
        unsigned v0 = *(const unsigned*)(H + (size_t)j0 * DIN + lo2);
        unsigned v1 = *(const unsigned*)(H + (size_t)j1 * DIN + lo2);
        unsigned v2 = *(const unsigned*)(H + (size_t)j2 * DIN + lo2);
        unsigned v3 = *(const unsigned*)(H + (size_t)j3 * DIN + lo2);
        float2 f0 = __half22float2(__builtin_bit_cast(__half2, v0));
        float2 f1 = __half22float2(__builtin_bit_cast(__half2, v1));
        float2 f2 = __half22float2(__builtin_bit_cast(__half2, v2));
        float2 f3 = __half22float2(__builtin_bit_cast(__half2, v3));
        a0 += f0.x + f1.x + f2.x + f3.x;
        a1 += f0.y + f1.y + f2.y + f3.y;
    }
    for (; p < pe; ++p) {
        unsigned v = *(const unsigned*)(H + (size_t)csr[p] * DIN + lo2);
        float2 f = __half22float2(__builtin_bit_cast(__half2, v));
        a0 += f.x; a1 += f.y;
    }
    __half2 o = __floats2half2_rn(a0, a1);
    *(unsigned*)(out + (size_t)node * DIN + lo2) = __builtin_bit_cast(unsigned, o);
}

// ------------------------------------------------------------------- GEMM
// C[M x 256] = A[M x K](fp16) @ W[K x 256](fp16) + bias; fp32 accumulate.
// BM=256 BN=128 BK=64, 4 waves, wave-tile 128x64. Staging via
// global_load_lds width=16: LDS dest linear (lane l -> base+l*16), swizzle
// applied on the per-lane GLOBAL source chunk (q ^ (row&7)); reads apply the
// same XOR -> conflict-free ds_read_b128, async staging, no VGPR roundtrip.
typedef __attribute__((ext_vector_type(8))) _Float16 f16x8;
typedef __attribute__((ext_vector_type(4))) float     f32x4;

__device__ __forceinline__ void gload16(const void* g, void* l) {
    __builtin_amdgcn_global_load_lds(
        (const __attribute__((address_space(1))) unsigned int*)g,
        (__attribute__((address_space(3))) unsigned int*)l, 16, 0, 0);
}

template<int K, int MODE>
__global__ __launch_bounds__(256, 2) void k_gemm_mfma(
        const __half* __restrict__ A,    // [Mpad x K]
        const __half* __restrict__ Wt,   // [256 x K] (transposed W)
        const float* __restrict__ bias,
        void* __restrict__ Cout, int M) {
    __shared__ __align__(16) __half As[BM * BK];   // 32 KB
    __shared__ __align__(16) __half Ws[BN * BK];   // 16 KB

    const int t    = threadIdx.x;
    const int lane = t & 63;
    const int wv   = t >> 6;          // wave id 0..3
    const int wr   = wv >> 1;
    const int wc   = wv & 1;
    const int brow = (int)blockIdx.x * BM;
    const int bcol = (int)blockIdx.y * BN;

    f32x4 acc[8][4] = {};

    // per-lane source-chunk swizzle: row r = ti*8 + (lane>>3), q = lane&7,
    // src chunk = q ^ (r&7) = (lane&7) ^ (lane>>3)
    const int rsub = lane >> 3;                  // row within 8-row group
    const int qsw  = (lane & 7) ^ rsub;          // swizzled source chunk

    for (int k0 = 0; k0 < K; k0 += BK) {
        // A tile: 32 insts (8/wave), each stages 8 rows x 128 B
#pragma unroll
        for (int i = 0; i < 8; ++i) {
            const int ti = wv * 8 + i;
            const int r  = ti * 8 + rsub;
            gload16(A + (size_t)(brow + r) * K + k0 + (qsw << 3),
                    (char*)As + ti * 1024);
        }
        // W tile: 16 insts (4/wave)
#pragma unroll
        for (int i = 0; i < 4; ++i) {
            const int tj = wv * 4 + i;
            const int c  = tj * 8 + rsub;
            gload16(Wt + (size_t)(bcol + c) * K + k0 + (qsw << 3),
                    (char*)Ws + tj * 1024);
        }
        __syncthreads();   // compiler drains vmcnt before barrier

#pragma unroll
        for (int kk = 0; kk < 2; ++kk) {
            const int qa = kk * 4 + (lane >> 4);
            f16x8 af[8], wf[4];
#pragma unroll
            for (int mi = 0; mi < 8; ++mi) {
                int r = wr * 128 + mi * 16 + (lane & 15);
                af[mi] = *(const f16x8*)((const char*)As + r * 128 + ((qa ^ (r & 7)) << 4));
            }
#pragma unroll
            for (int ni = 0; ni < 4; ++ni) {
                int c = wc * 64 + ni * 16 + (lane & 15);
                wf[ni] = *(const f16x8*)((const char*)Ws + c * 128 + ((qa ^ (c & 7)) << 4));
            }
#pragma unroll
            for (int mi = 0; mi < 8; ++mi)
#pragma unroll
                for (int ni = 0; ni < 4; ++ni)
                    acc[mi][ni] = __builtin_amdgcn_mfma_f32_16x16x32_f16(af[mi], wf[ni], acc[mi][ni], 0, 0, 0);
        }
        __syncthreads();
    }

#pragma unroll
    for (int ni = 0; ni < 4; ++ni) {
        const int c = bcol + wc * 64 + ni * 16 + (lane & 15);
        const float bz = bias[c];
#pragma unroll
        for (int mi = 0; mi < 8; ++mi) {
            const int r0 = brow + wr * 128 + mi * 16 + ((lane >> 4) << 2);
#pragma unroll
            for (int j = 0; j < 4; ++j) {
                int row = r0 + j;
                if (row < M) {
                    float v = acc[mi][ni][j] + bz;
                    if (MODE == 0) {
                        v = fmaxf(v, 0.f);
                        ((__half*)Cout)[(size_t)row * DH + c] = __float2half(v);
                    } else {
                        ((float*)Cout)[(size_t)row * DH + c] = v;
                    }
                }
            }
        }
    }
}

// ------------------------------------------------------------------ launch
static inline size_t align256(size_t x) { return (x + 255) & ~(size_t)255; }

extern "C" void kernel_launch(void* const* d_in, const int* in_sizes, int n_in,
                              void* d_out, int out_size, void* d_ws, size_t ws_size,
                              hipStream_t stream) {
    const float* x   = (const float*)d_in[0];
    const int*   ei  = (const int*)d_in[1];
    const float* W[6]  = {(const float*)d_in[2], (const float*)d_in[4],
                          (const float*)d_in[6], (const float*)d_in[8],
                          (const float*)d_in[10], (const float*)d_in[12]};
    const float* Bv[6] = {(const float*)d_in[3], (const float*)d_in[5],
                          (const float*)d_in[7], (const float*)d_in[9],
                          (const float*)d_in[11], (const float*)d_in[13]};

    const int N = in_sizes[0] / DIN;
    const int E = in_sizes[1] / 2;
    const int Mpad = ((N + BM - 1) / BM) * BM;
    const int* src = ei;
    const int* dst = ei + E;
    const int nbuck  = (N + BNODES - 1) / BNODES;
    const int chunkE = (E + PBLK - 1) / PBLK;

    char* ws = (char*)d_ws;
    __half* A1 = (__half*)ws; ws += align256((size_t)Mpad * DIN * 2);
    __half* Ah = (__half*)ws; ws += align256((size_t)Mpad * DH * 2);
    __half* T  = (__half*)ws; ws += align256((size_t)Mpad * DH * 2);
    __half* Hh = (__half*)ws; ws += align256((size_t)Mpad * DH * 2);
    __half* Xh = (__half*)T;          // alias: T first written after Xh last read
    uint2* pairb = (uint2*)Ah;        // alias: Ah first written after pairb dead
    __half* Wh[6];
    const int Ks[6] = {DIN, DH, DH, DH, DH, DH};
    for (int i = 0; i < 6; ++i) {
        Wh[i] = (__half*)ws; ws += align256((size_t)Ks[i] * DH * 2);
    }
    int* cntMat  = (int*)ws; ws += align256((size_t)PBLK * MAXB * 4);
    int* baseMat = (int*)ws; ws += align256((size_t)PBLK * MAXB * 4);
    int* bbase   = (int*)ws; ws += align256((size_t)(MAXB + 1) * 4);
    int* rp      = (int*)ws; ws += align256((size_t)(N + 1) * 4);
    int* csr     = (int*)ws; ws += align256((size_t)E * 4);
    float* O = (float*)d_out;

    // --- merged prep (weight transpose/cast + x cast) ---
    PrepArgs pa;
    for (int i = 0; i < 6; ++i) { pa.W[i] = W[i]; pa.Wh[i] = Wh[i]; }
    pa.x = x; pa.xh = Xh;
    const int n4 = N * DIN / 4;
    const int castBlocks = (n4 + 255) / 256;
    k_prep<<<1408 + castBlocks, 256, 0, stream>>>(pa, n4);

    // --- CSR build (counting sort; no global atomics) ---
    k_bhist<<<PBLK, 1024, 0, stream>>>(dst, cntMat, E, nbuck, chunkE);
    k_bscan<<<1, 256, 0, stream>>>(cntMat, bbase, baseMat, nbuck, E);
    k_bpart<<<PBLK, 1024, 0, stream>>>(src, dst, baseMat, pairb, E, nbuck, chunkE);
    k_bcsr<<<nbuck, 1024, 0, stream>>>(pairb, bbase, rp, csr, N, E);

    const int gAgg = (N + 3) / 4;
    dim3 gGemm(Mpad / BM, DH / BN);

    // --- layer 1 ---
    k_aggh128<<<gAgg, 256, 0, stream>>>(Xh, rp, csr, A1, N);
    k_gemm_mfma<DIN, 0><<<gGemm, 256, 0, stream>>>(A1, Wh[0], Bv[0], T, N);
    k_gemm_mfma<DH,  0><<<gGemm, 256, 0, stream>>>(T,  Wh[1], Bv[1], Hh, N);
    // --- layer 2 ---
    k_aggh256<<<gAgg, 256, 0, stream>>>(Hh, rp, csr, Ah, N);
    k_gemm_mfma<DH,  0><<<gGemm, 256, 0, stream>>>(Ah, Wh[2], Bv[2], T, N);
    k_gemm_mfma<DH,  0><<<gGemm, 256, 0, stream>>>(T,  Wh[3], Bv[3], Hh, N);
    // --- layer 3 ---
    k_aggh256<<<gAgg, 256, 0, stream>>>(Hh, rp, csr, Ah, N);
    k_gemm_mfma<DH,  0><<<gGemm, 256, 0, stream>>>(Ah, Wh[4], Bv[4], T, N);
    k_gemm_mfma<DH,  1><<<gGemm, 256, 0, stream>>>(T,  Wh[5], Bv[5], O, N);
}